// Round 1
// baseline (540.894 us; speedup 1.0000x reference)
//
#include <hip/hip_runtime.h>
#include <math.h>

#define WT_LEN 512
#define N_WT 20
#define B_ 16
#define T_ 262144           // 2^18 per row
#define TOTAL (B_ * T_)     // 4194304
#define CHUNK 8192          // 2^13 elems per block
#define NCHR 32             // chunks per row
#define NCH  512            // total chunks

// inc = (pitch / 44100) * 512 ; f32 division correctly rounded (verified R1/R2).
__device__ __forceinline__ float to_inc1(float x) {
    return (x / 44100.0f) * 512.0f;
}
__device__ __forceinline__ float4 to_inc4(float4 p) {
    float4 r;
    r.x = to_inc1(p.x); r.y = to_inc1(p.y);
    r.z = to_inc1(p.z); r.w = to_inc1(p.w);
    return r;
}

// ---------------------------------------------------------------------------
// U: per-chunk exact adjacent-pair tree reduction -> A13[chunk]. (unchanged)
// ---------------------------------------------------------------------------
__global__ __launch_bounds__(1024) void up_kernel(
        const float* __restrict__ pitch, float* __restrict__ A13) {
    __shared__ float red[2048];
    const int t = threadIdx.x;
    const size_t g0 = (size_t)blockIdx.x * CHUNK;

    const float4* p4 = (const float4*)(pitch + g0);
    float4 v0 = to_inc4(p4[2 * t]);
    float4 v1 = to_inc4(p4[2 * t + 1]);
    float t0 = v0.x + v0.y, t1 = v0.z + v0.w;
    float t2 = v1.x + v1.y, t3 = v1.z + v1.w;
    red[t] = (t0 + t1) + (t2 + t3);        // A3[t]
    __syncthreads();
    int off_prev = 0, off = 1024;
    for (int sz = 512; sz >= 1; sz >>= 1) {   // levels 4..13
        if (t < sz) red[off + t] = red[off_prev + 2 * t] + red[off_prev + 2 * t + 1];
        __syncthreads();
        off_prev = off; off += sz;
    }
    if (t == 0) A13[blockIdx.x] = red[2046];
}

// ---------------------------------------------------------------------------
// M: exact odd-even scan of chunk totals -> S13 + X0; tanh'd transposed
// wavetable WTT. (unchanged)
// ---------------------------------------------------------------------------
__global__ __launch_bounds__(1024) void mid_kernel(
        const float* __restrict__ A13, const float* __restrict__ pitch,
        const float* __restrict__ wtg, float* __restrict__ S13,
        float* __restrict__ X0, float* __restrict__ WTT) {
    int r = threadIdx.x;
    if (r < B_) {
        float l0[32], l1[16], l2[8], l3[4], l4[2], l5;
        for (int i = 0; i < 32; ++i) l0[i] = A13[r * 32 + i];
        for (int i = 0; i < 16; ++i) l1[i] = l0[2 * i] + l0[2 * i + 1];
        for (int i = 0; i < 8;  ++i) l2[i] = l1[2 * i] + l1[2 * i + 1];
        for (int i = 0; i < 4;  ++i) l3[i] = l2[2 * i] + l2[2 * i + 1];
        for (int i = 0; i < 2;  ++i) l4[i] = l3[2 * i] + l3[2 * i + 1];
        l5 = l4[0] + l4[1];

        float s4[2], s3[4], s2[8], s1[16], s0[32];
        s4[0] = l4[0]; s4[1] = l5;
        s3[0] = l3[0];
        for (int i = 0; i < 2; ++i) {
            s3[2 * i + 1] = s4[i];
            if (2 * i + 2 < 4) s3[2 * i + 2] = s4[i] + l3[2 * i + 2];
        }
        s2[0] = l2[0];
        for (int i = 0; i < 4; ++i) {
            s2[2 * i + 1] = s3[i];
            if (2 * i + 2 < 8) s2[2 * i + 2] = s3[i] + l2[2 * i + 2];
        }
        s1[0] = l1[0];
        for (int i = 0; i < 8; ++i) {
            s1[2 * i + 1] = s2[i];
            if (2 * i + 2 < 16) s1[2 * i + 2] = s2[i] + l1[2 * i + 2];
        }
        s0[0] = l0[0];
        for (int i = 0; i < 16; ++i) {
            s0[2 * i + 1] = s1[i];
            if (2 * i + 2 < 32) s0[2 * i + 2] = s1[i] + l0[2 * i + 2];
        }
        for (int i = 0; i < 32; ++i) S13[r * 32 + i] = s0[i];
        X0[r] = to_inc1(pitch[(size_t)r * T_]);
    }
    // wavetable prep: transpose + tanh once
    for (int e = threadIdx.x; e < WT_LEN * N_WT; e += 1024) {
        int c = e / WT_LEN;
        int i = e - c * WT_LEN;
        float v = wtg[e];
        if (c >= 4) v = tanhf(v);
        WTT[i * N_WT + c] = v;
    }
}

// ---------------------------------------------------------------------------
// D+MIX fused: identical scan math as old down_kernel (bit-exact), but the
// per-thread 8 scan outputs stay in registers and feed the wavetable mix
// directly. Removes the 16.8 MB S-write + 16.8 MB S-read round trip through
// d_out and one kernel launch. LDS = 8 KB scan + 40 KB wavetable = 48 KB.
// Wavetable staged from WTT (already tanh'd/transposed); visibility of the
// staging writes is covered by the scan's own __syncthreads chain.
// ---------------------------------------------------------------------------
__global__ __launch_bounds__(1024) void downmix_kernel(
        const float* __restrict__ pitch, const float* __restrict__ S13,
        const float* __restrict__ X0v, const float* __restrict__ amp,
        const float* __restrict__ att, const float* __restrict__ WTT,
        float* __restrict__ out) {
    __shared__ float a[2048];                 // scan levels 3..13
    __shared__ float wt_lds[WT_LEN * N_WT];   // [i][c], 40 KB
    const int t = threadIdx.x;
    const int c = blockIdx.x;
    const size_t g0 = (size_t)c * CHUNK;

    // stage wavetable: 2560 float4 over 1024 threads
    {
        const float4* src = (const float4*)WTT;
        float4* dst = (float4*)wt_lds;
        dst[t]        = src[t];
        dst[t + 1024] = src[t + 1024];
        if (t < 512) dst[t + 2048] = src[t + 2048];
    }

    const float4* p4 = (const float4*)(pitch + g0);
    float4 va = to_inc4(p4[2 * t]);
    float4 vb = to_inc4(p4[2 * t + 1]);
    float x0 = va.x, x2 = va.z, x4 = vb.x, x6 = vb.z;
    float t0 = va.x + va.y, t1 = va.z + va.w;
    float t2 = vb.x + vb.y, t3 = vb.z + vb.w;
    float u0 = t0 + t1, u1 = t2 + t3;
    a[t] = u0 + u1;                 // A3[t]
    __syncthreads();

    // up-sweep levels 4..12
    int bp = 0, b = 1024;
    for (int sz = 512; sz >= 2; sz >>= 1) {
        if (t < sz) a[b + t] = a[bp + 2 * t] + a[bp + 2 * t + 1];
        __syncthreads();
        bp = b; b += sz;
    }

    const float P   = (c & (NCHR - 1)) ? S13[c - 1] : 0.0f;
    const float T13 = S13[c];
    if (t == 0) {
        a[2044] = P + a[2044];      // s12[0] = P + A12[0]
        a[2045] = T13;              // s12[1] = S13[c]
    }
    __syncthreads();

    // down-sweep levels 11..3, in place per slice (identical to old down)
    const int offk[10] = {0, 1024, 1536, 1792, 1920, 1984, 2016, 2032, 2040, 2044};
    for (int k = 11; k >= 3; --k) {
        int m = 1 << (13 - k), half = m >> 1;
        int bk = offk[k - 3], bn = offk[k - 2];
        if (t < half) {
            float sn = a[bn + t];                  // s_{k+1}[t], finalized
            int j = 2 * t + 2;
            float av = (j < m) ? a[bk + j] : 0.0f;
            a[bk + 2 * t + 1] = sn;
            if (j < m) a[bk + j] = sn + av;
        }
        if (t == 0) a[bk] = P + a[bk];             // s_k[0]
        __syncthreads();
    }

    // per-thread scan outputs, exactly as the old down_kernel stored them
    float S3prev = t ? a[t - 1] : P;
    float s3t = a[t];
    float s1a = S3prev + t0;        // s1[4t]
    float s2a = S3prev + u0;        // s2[2t]
    float s1c = s2a + t2;           // s1[4t+2]
    (void)t1; (void)t3; (void)u1;

    float Sv[8] = { S3prev + x0, s1a, s1a + x2, s2a,
                    s2a + x4,    s1c, s1c + x6, s3t };

    // ---- mix (identical FP op order to old mix_kernel) ----
    const float x0row = X0v[c >> 5];          // row = (g>>18) is uniform per chunk
    const float4* a4  = (const float4*)(att + (size_t)(g0 + 8 * (size_t)t) * N_WT);
    const float4* am4 = (const float4*)(amp + g0);
    float4 am0 = am4[2 * t];
    float4 am1 = am4[2 * t + 1];
    float ampv[8] = {am0.x, am0.y, am0.z, am0.w, am1.x, am1.y, am1.z, am1.w};

    float res[8];
#pragma unroll
    for (int j = 0; j < 8; ++j) {
        float y = Sv[j] - x0row;              // index = cumsum - increment[:, :1]

        // exact fmod(y, 512)
        float qf  = floorf(y * (1.0f / 512.0f));
        float idx = fmaf(-512.0f, qf, y);
        if (idx < 0.0f)    idx += 512.0f;
        if (idx >= 512.0f) idx -= 512.0f;

        float fl0   = floorf(idx);
        float alpha = idx - fl0;
        int il = ((int)fl0) & (WT_LEN - 1);
        int ih = (il + (alpha > 0.0f ? 1 : 0)) & (WT_LEN - 1);

        const float4* lo4 = (const float4*)(&wt_lds[il * N_WT]);
        const float4* hi4 = (const float4*)(&wt_lds[ih * N_WT]);

        float acc = 0.0f;
#pragma unroll
        for (int v = 0; v < 5; ++v) {
            float4 lo = lo4[v];
            float4 hi = hi4[v];
            float4 at = a4[5 * j + v];
            acc += at.x * (lo.x + alpha * (hi.x - lo.x));
            acc += at.y * (lo.y + alpha * (hi.y - lo.y));
            acc += at.z * (lo.z + alpha * (hi.z - lo.z));
            acc += at.w * (lo.w + alpha * (hi.w - lo.w));
        }
        res[j] = acc * ampv[j];
    }

    float4* q4 = (float4*)(out + g0);
    q4[2 * t]     = make_float4(res[0], res[1], res[2], res[3]);
    q4[2 * t + 1] = make_float4(res[4], res[5], res[6], res[7]);
}

// ---------------------------------------------------------------------------
extern "C" void kernel_launch(void* const* d_in, const int* in_sizes, int n_in,
                              void* d_out, int out_size, void* d_ws, size_t ws_size,
                              hipStream_t stream) {
    const float* pitch = (const float*)d_in[0];
    const float* amp   = (const float*)d_in[1];
    const float* att   = (const float*)d_in[2];
    const float* wtg   = (const float*)d_in[3];

    float* A13 = (float*)d_ws;          // [512]
    float* S13 = A13 + NCH;             // [512]
    float* X0  = S13 + NCH;             // [16]
    float* WTT = X0 + 64;               // [10240] (16-float aligned)

    up_kernel<<<NCH, 1024, 0, stream>>>(pitch, A13);
    mid_kernel<<<1, 1024, 0, stream>>>(A13, pitch, wtg, S13, X0, WTT);
    downmix_kernel<<<NCH, 1024, 0, stream>>>(pitch, S13, X0, amp, att, WTT,
                                             (float*)d_out);
}

// Round 3
// 485.112 us; speedup vs baseline: 1.1150x; 1.1150x over previous
//
#include <hip/hip_runtime.h>
#include <math.h>

#define WT_LEN 512
#define N_WT 20
#define B_ 16
#define T_ 262144           // 2^18 per row
#define TOTAL (B_ * T_)     // 4194304
#define CHUNK 8192          // 2^13 elems per block
#define NCHR 32             // chunks per row
#define NCH  512            // total chunks

// inc = (pitch / 44100) * 512 ; f32 division correctly rounded (verified R1/R2).
__device__ __forceinline__ float to_inc1(float x) {
    return (x / 44100.0f) * 512.0f;
}
__device__ __forceinline__ float4 to_inc4(float4 p) {
    float4 r;
    r.x = to_inc1(p.x); r.y = to_inc1(p.y);
    r.z = to_inc1(p.z); r.w = to_inc1(p.w);
    return r;
}

// ---------------------------------------------------------------------------
// U: per-chunk exact adjacent-pair tree reduction -> A13[chunk]. (unchanged)
// ---------------------------------------------------------------------------
__global__ __launch_bounds__(1024) void up_kernel(
        const float* __restrict__ pitch, float* __restrict__ A13) {
    __shared__ float red[2048];
    const int t = threadIdx.x;
    const size_t g0 = (size_t)blockIdx.x * CHUNK;

    const float4* p4 = (const float4*)(pitch + g0);
    float4 v0 = to_inc4(p4[2 * t]);
    float4 v1 = to_inc4(p4[2 * t + 1]);
    float t0 = v0.x + v0.y, t1 = v0.z + v0.w;
    float t2 = v1.x + v1.y, t3 = v1.z + v1.w;
    red[t] = (t0 + t1) + (t2 + t3);        // A3[t]
    __syncthreads();
    int off_prev = 0, off = 1024;
    for (int sz = 512; sz >= 1; sz >>= 1) {   // levels 4..13
        if (t < sz) red[off + t] = red[off_prev + 2 * t] + red[off_prev + 2 * t + 1];
        __syncthreads();
        off_prev = off; off += sz;
    }
    if (t == 0) A13[blockIdx.x] = red[2046];
}

// ---------------------------------------------------------------------------
// Compact, bit-exact evaluation of mid's odd-even scan: s0[j] over one row's
// 32 chunk totals. l_k trees are the identical pairwise associations; the
// descent adds l_k in the identical (((base+l3)+l2)+l1)+l0 nesting.
// Verified index-by-index against mid's recursion (s0[1],[2],[3],[4],[5],
// [6],[30],[31]).
// ---------------------------------------------------------------------------
__device__ __forceinline__ float l1f(const float* A, int m) { return A[2*m] + A[2*m+1]; }
__device__ __forceinline__ float l2f(const float* A, int m) { return l1f(A,2*m) + l1f(A,2*m+1); }
__device__ __forceinline__ float l3f(const float* A, int m) { return l2f(A,2*m) + l2f(A,2*m+1); }
__device__ __forceinline__ float l4f(const float* A, int m) { return l3f(A,2*m) + l3f(A,2*m+1); }

__device__ float s0_of(const float* __restrict__ A, int j) {
    if (j == 0) return A[0];
    float p0 = 0.f, p1 = 0.f, p2 = 0.f, p3 = 0.f;
    bool h0 = false, h1 = false, h2 = false, h3 = false;
    float base;
    int m = j;
    // level 0 -> 1
    if ((m & 1) == 0) { p0 = A[m]; h0 = true; m = (m - 2) >> 1; }
    else m >>= 1;
    if (m == 0) { base = l1f(A, 0); goto comb; }
    // level 1 -> 2
    if ((m & 1) == 0) { p1 = l1f(A, m); h1 = true; m = (m - 2) >> 1; }
    else m >>= 1;
    if (m == 0) { base = l2f(A, 0); goto comb; }
    // level 2 -> 3
    if ((m & 1) == 0) { p2 = l2f(A, m); h2 = true; m = (m - 2) >> 1; }
    else m >>= 1;
    if (m == 0) { base = l3f(A, 0); goto comb; }
    // level 3 -> 4
    if ((m & 1) == 0) { p3 = l3f(A, m); h3 = true; m = (m - 2) >> 1; }
    else m >>= 1;
    base = (m == 0) ? l4f(A, 0) : (l4f(A, 0) + l4f(A, 1));   // s4[0] / s4[1]=l5
comb:
    if (h3) base += p3;
    if (h2) base += p2;
    if (h1) base += p1;
    if (h0) base += p0;
    return base;
}

// ---------------------------------------------------------------------------
// D v3: identical scan to the proven down_kernel, but self-sufficient:
// thread 0 derives P = s0[lc-1] and T13 = s0[lc] from A13 (bit-exact vs the
// old mid_kernel's S13), removing the 1-block mid launch bubble.
// P/T13 are only ever consumed on thread 0 (seed, downsweep head, S3prev).
// __launch_bounds__(1024, 8) pins VGPR <= 64 so the cold thread-0 scan path
// spills (cheaply, thread-0-only) rather than costing the block 2 wg/CU.
// ---------------------------------------------------------------------------
__global__ __launch_bounds__(1024, 8) void down_kernel(
        const float* __restrict__ pitch, const float* __restrict__ A13,
        float* __restrict__ sout) {
    __shared__ float a[2048];       // levels 3..13
    const int t = threadIdx.x;
    const int c = blockIdx.x;
    const size_t g0 = (size_t)c * CHUNK;

    // thread 0: chunk prefix + chunk-inclusive total from A13 (L2-hot, 128 B/row)
    float P = 0.0f, T13 = 0.0f;
    if (t == 0) {
        const float* A = A13 + ((c >> 5) << 5);   // this row's 32 chunk totals
        const int lc = c & (NCHR - 1);
        if (lc) P = s0_of(A, lc - 1);
        T13 = s0_of(A, lc);
    }

    const float4* p4 = (const float4*)(pitch + g0);
    float4 va = to_inc4(p4[2 * t]);
    float4 vb = to_inc4(p4[2 * t + 1]);
    float x0 = va.x, x2 = va.z, x4 = vb.x, x6 = vb.z;
    float t0 = va.x + va.y, t1 = va.z + va.w;
    float t2 = vb.x + vb.y, t3 = vb.z + vb.w;
    float u0 = t0 + t1, u1 = t2 + t3;
    a[t] = u0 + u1;                 // A3[t]
    __syncthreads();

    // up-sweep levels 4..12
    int bp = 0, b = 1024;
    for (int sz = 512; sz >= 2; sz >>= 1) {
        if (t < sz) a[b + t] = a[bp + 2 * t] + a[bp + 2 * t + 1];
        __syncthreads();
        bp = b; b += sz;
    }

    if (t == 0) {
        a[2044] = P + a[2044];      // s12[0] = P + A12[0]
        a[2045] = T13;              // s12[1] = S13[c]
    }
    __syncthreads();

    // down-sweep levels 11..3, in place per slice (identical to proven down)
    const int offk[10] = {0, 1024, 1536, 1792, 1920, 1984, 2016, 2032, 2040, 2044};
    for (int k = 11; k >= 3; --k) {
        int m = 1 << (13 - k), half = m >> 1;
        int bk = offk[k - 3], bn = offk[k - 2];
        if (t < half) {
            float sn = a[bn + t];                  // s_{k+1}[t], finalized
            int j = 2 * t + 2;
            float av = (j < m) ? a[bk + j] : 0.0f;
            a[bk + 2 * t + 1] = sn;
            if (j < m) a[bk + j] = sn + av;
        }
        if (t == 0) a[bk] = P + a[bk];             // s_k[0]
        __syncthreads();
    }

    float S3prev = t ? a[t - 1] : P;
    float s3t = a[t];
    float s1a = S3prev + t0;        // s1[4t]
    float s2a = S3prev + u0;        // s2[2t]
    float s1c = s2a + t2;           // s1[4t+2]
    (void)t1; (void)t3; (void)u1;

    float4* q4 = (float4*)(sout + g0);
    q4[2 * t]     = make_float4(S3prev + x0, s1a, s1a + x2, s2a);
    q4[2 * t + 1] = make_float4(s2a + x4, s1c, s1c + x6, s3t);
}

// ---------------------------------------------------------------------------
// mix v3: identical mix math/occupancy shape to the proven mix_kernel
// (512 thr, 40 KB wt LDS, 4 wg/CU), but self-sufficient: builds the tanh'd
// transposed wavetable and X0 per block from wtg/pitch (deterministic ->
// values identical to the old mid-built WTT). Reads S from ws, writes out
// (no in-place RMW; also makes mix idempotent for future double-launch A/B).
// ---------------------------------------------------------------------------
__global__ __launch_bounds__(512) void mix_kernel(
        const float* __restrict__ Sbuf, const float* __restrict__ pitch,
        const float* __restrict__ amp, const float* __restrict__ att,
        const float* __restrict__ wtg, float* __restrict__ out, int ntiles) {
    __shared__ float wt_lds[WT_LEN * N_WT];   // [i][c], 40 KB
    __shared__ float x0s[B_];
    for (int e = threadIdx.x; e < WT_LEN * N_WT; e += 512) {
        int c = e >> 9;               // wtg is [N_WT][WT_LEN]
        int i = e & (WT_LEN - 1);
        float v = wtg[e];
        if (c >= 4) v = tanhf(v);
        wt_lds[i * N_WT + c] = v;
    }
    if (threadIdx.x < B_)
        x0s[threadIdx.x] = to_inc1(pitch[(size_t)threadIdx.x << 18]);
    __syncthreads();

    for (int tile = blockIdx.x; tile < ntiles; tile += gridDim.x) {
        int gid = tile * 512 + threadIdx.x;
        int row = gid >> 18;
        float S = Sbuf[gid];
        float y = S - x0s[row];           // index = cumsum - increment[:, :1]

        // exact fmod(y, 512)
        float qf  = floorf(y * (1.0f / 512.0f));
        float idx = fmaf(-512.0f, qf, y);
        if (idx < 0.0f)    idx += 512.0f;
        if (idx >= 512.0f) idx -= 512.0f;

        float fl0   = floorf(idx);
        float alpha = idx - fl0;
        int il = ((int)fl0) & (WT_LEN - 1);
        int ih = (il + (alpha > 0.0f ? 1 : 0)) & (WT_LEN - 1);

        const float4* lo4 = (const float4*)(&wt_lds[il * N_WT]);
        const float4* hi4 = (const float4*)(&wt_lds[ih * N_WT]);
        const float4* a4  = (const float4*)(att + (size_t)gid * N_WT);

        float acc = 0.0f;
#pragma unroll
        for (int v = 0; v < 5; ++v) {
            float4 lo = lo4[v];
            float4 hi = hi4[v];
            float4 at = a4[v];
            acc += at.x * (lo.x + alpha * (hi.x - lo.x));
            acc += at.y * (lo.y + alpha * (hi.y - lo.y));
            acc += at.z * (lo.z + alpha * (hi.z - lo.z));
            acc += at.w * (lo.w + alpha * (hi.w - lo.w));
        }
        out[gid] = acc * amp[gid];
    }
}

// ---------------------------------------------------------------------------
extern "C" void kernel_launch(void* const* d_in, const int* in_sizes, int n_in,
                              void* d_out, int out_size, void* d_ws, size_t ws_size,
                              hipStream_t stream) {
    const float* pitch = (const float*)d_in[0];
    const float* amp   = (const float*)d_in[1];
    const float* att   = (const float*)d_in[2];
    const float* wtg   = (const float*)d_in[3];

    float* A13 = (float*)d_ws;          // [512]
    float* S   = A13 + 1024;            // [TOTAL], 4 KB-aligned

    up_kernel<<<NCH, 1024, 0, stream>>>(pitch, A13);
    down_kernel<<<NCH, 1024, 0, stream>>>(pitch, A13, S);
    mix_kernel<<<1024, 512, 0, stream>>>(S, pitch, amp, att, wtg,
                                         (float*)d_out, TOTAL / 512);
}

// Round 4
// 484.471 us; speedup vs baseline: 1.1165x; 1.0013x over previous
//
#include <hip/hip_runtime.h>
#include <math.h>

#define WT_LEN 512
#define N_WT 20
#define B_ 16
#define T_ 262144           // 2^18 per row
#define TOTAL (B_ * T_)     // 4194304
#define CHUNK 8192          // 2^13 elems per block
#define NCHR 32             // chunks per row
#define NCH  512            // total chunks

// inc = (pitch / 44100) * 512 ; f32 division correctly rounded (verified R1/R2).
__device__ __forceinline__ float to_inc1(float x) {
    return (x / 44100.0f) * 512.0f;
}
__device__ __forceinline__ float4 to_inc4(float4 p) {
    float4 r;
    r.x = to_inc1(p.x); r.y = to_inc1(p.y);
    r.z = to_inc1(p.z); r.w = to_inc1(p.w);
    return r;
}

// ---------------------------------------------------------------------------
// U: per-chunk exact adjacent-pair tree reduction -> A13[chunk]. (unchanged)
// ---------------------------------------------------------------------------
__global__ __launch_bounds__(1024) void up_kernel(
        const float* __restrict__ pitch, float* __restrict__ A13) {
    __shared__ float red[2048];
    const int t = threadIdx.x;
    const size_t g0 = (size_t)blockIdx.x * CHUNK;

    const float4* p4 = (const float4*)(pitch + g0);
    float4 v0 = to_inc4(p4[2 * t]);
    float4 v1 = to_inc4(p4[2 * t + 1]);
    float t0 = v0.x + v0.y, t1 = v0.z + v0.w;
    float t2 = v1.x + v1.y, t3 = v1.z + v1.w;
    red[t] = (t0 + t1) + (t2 + t3);        // A3[t]
    __syncthreads();
    int off_prev = 0, off = 1024;
    for (int sz = 512; sz >= 1; sz >>= 1) {   // levels 4..13
        if (t < sz) red[off + t] = red[off_prev + 2 * t] + red[off_prev + 2 * t + 1];
        __syncthreads();
        off_prev = off; off += sz;
    }
    if (t == 0) A13[blockIdx.x] = red[2046];
}

// ---------------------------------------------------------------------------
// Compact, bit-exact evaluation of mid's odd-even scan: s0[j] over one row's
// 32 chunk totals. (unchanged, verified vs mid recursion)
// ---------------------------------------------------------------------------
__device__ __forceinline__ float l1f(const float* A, int m) { return A[2*m] + A[2*m+1]; }
__device__ __forceinline__ float l2f(const float* A, int m) { return l1f(A,2*m) + l1f(A,2*m+1); }
__device__ __forceinline__ float l3f(const float* A, int m) { return l2f(A,2*m) + l2f(A,2*m+1); }
__device__ __forceinline__ float l4f(const float* A, int m) { return l3f(A,2*m) + l3f(A,2*m+1); }

__device__ float s0_of(const float* __restrict__ A, int j) {
    if (j == 0) return A[0];
    float p0 = 0.f, p1 = 0.f, p2 = 0.f, p3 = 0.f;
    bool h0 = false, h1 = false, h2 = false, h3 = false;
    float base;
    int m = j;
    if ((m & 1) == 0) { p0 = A[m]; h0 = true; m = (m - 2) >> 1; }
    else m >>= 1;
    if (m == 0) { base = l1f(A, 0); goto comb; }
    if ((m & 1) == 0) { p1 = l1f(A, m); h1 = true; m = (m - 2) >> 1; }
    else m >>= 1;
    if (m == 0) { base = l2f(A, 0); goto comb; }
    if ((m & 1) == 0) { p2 = l2f(A, m); h2 = true; m = (m - 2) >> 1; }
    else m >>= 1;
    if (m == 0) { base = l3f(A, 0); goto comb; }
    if ((m & 1) == 0) { p3 = l3f(A, m); h3 = true; m = (m - 2) >> 1; }
    else m >>= 1;
    base = (m == 0) ? l4f(A, 0) : (l4f(A, 0) + l4f(A, 1));   // s4[0] / s4[1]=l5
comb:
    if (h3) base += p3;
    if (h2) base += p2;
    if (h1) base += p1;
    if (h0) base += p0;
    return base;
}

// ---------------------------------------------------------------------------
// D v3: self-sufficient exact scan (unchanged from R3's passing version).
// ---------------------------------------------------------------------------
__global__ __launch_bounds__(1024, 8) void down_kernel(
        const float* __restrict__ pitch, const float* __restrict__ A13,
        float* __restrict__ sout) {
    __shared__ float a[2048];       // levels 3..13
    const int t = threadIdx.x;
    const int c = blockIdx.x;
    const size_t g0 = (size_t)c * CHUNK;

    float P = 0.0f, T13 = 0.0f;
    if (t == 0) {
        const float* A = A13 + ((c >> 5) << 5);   // this row's 32 chunk totals
        const int lc = c & (NCHR - 1);
        if (lc) P = s0_of(A, lc - 1);
        T13 = s0_of(A, lc);
    }

    const float4* p4 = (const float4*)(pitch + g0);
    float4 va = to_inc4(p4[2 * t]);
    float4 vb = to_inc4(p4[2 * t + 1]);
    float x0 = va.x, x2 = va.z, x4 = vb.x, x6 = vb.z;
    float t0 = va.x + va.y, t1 = va.z + va.w;
    float t2 = vb.x + vb.y, t3 = vb.z + vb.w;
    float u0 = t0 + t1, u1 = t2 + t3;
    a[t] = u0 + u1;                 // A3[t]
    __syncthreads();

    int bp = 0, b = 1024;
    for (int sz = 512; sz >= 2; sz >>= 1) {
        if (t < sz) a[b + t] = a[bp + 2 * t] + a[bp + 2 * t + 1];
        __syncthreads();
        bp = b; b += sz;
    }

    if (t == 0) {
        a[2044] = P + a[2044];      // s12[0] = P + A12[0]
        a[2045] = T13;              // s12[1] = S13[c]
    }
    __syncthreads();

    const int offk[10] = {0, 1024, 1536, 1792, 1920, 1984, 2016, 2032, 2040, 2044};
    for (int k = 11; k >= 3; --k) {
        int m = 1 << (13 - k), half = m >> 1;
        int bk = offk[k - 3], bn = offk[k - 2];
        if (t < half) {
            float sn = a[bn + t];                  // s_{k+1}[t], finalized
            int j = 2 * t + 2;
            float av = (j < m) ? a[bk + j] : 0.0f;
            a[bk + 2 * t + 1] = sn;
            if (j < m) a[bk + j] = sn + av;
        }
        if (t == 0) a[bk] = P + a[bk];             // s_k[0]
        __syncthreads();
    }

    float S3prev = t ? a[t - 1] : P;
    float s3t = a[t];
    float s1a = S3prev + t0;        // s1[4t]
    float s2a = S3prev + u0;        // s2[2t]
    float s1c = s2a + t2;           // s1[4t+2]
    (void)t1; (void)t3; (void)u1;

    float4* q4 = (float4*)(sout + g0);
    q4[2 * t]     = make_float4(S3prev + x0, s1a, s1a + x2, s2a);
    q4[2 * t + 1] = make_float4(s2a + x4, s1c, s1c + x6, s3t);
}

// ---------------------------------------------------------------------------
// mix v4: attention stream made lane-coalesced via wave-private LDS bounce.
// Old pattern: 5x global_load_dwordx4 with 80 B lane stride -> ~70 cache-line
// transactions per instr (4.4x blowup) on the stream that is 87% of bytes.
// New: each wave stages its 64-elem att micro-tile (5120 B) with 5 fully
// coalesced float4 loads into its own LDS slice (no barriers: wave-private,
// same-wave LDS ordering is compiler-enforced), then reads per-element at
// stride-20 (banks (20*lane+4k)%32 tile all 32 banks evenly -> optimal b128).
// LDS = 40 KB wt + 40 KB att slices = 80 KB exactly -> 2 blocks/CU (16
// waves, barrier-free drifting). x0 moved out of LDS: row is uniform per
// 512-elem tile -> one scalar load per tile, same expression -> bit-exact.
// ---------------------------------------------------------------------------
__global__ __launch_bounds__(512) void mix_kernel(
        const float* __restrict__ Sbuf, const float* __restrict__ pitch,
        const float* __restrict__ amp, const float* __restrict__ att,
        const float* __restrict__ wtg, float* __restrict__ out, int ntiles) {
    __shared__ float wt_lds[WT_LEN * N_WT];    // [i][c], 40 KB
    __shared__ float att_lds[512 * N_WT];      // 8 wave slices x (64 elems x 20), 40 KB
    const int tid  = threadIdx.x;
    const int lane = tid & 63;
    const int w    = tid >> 6;

    for (int e = tid; e < WT_LEN * N_WT; e += 512) {
        int c = e >> 9;               // wtg is [N_WT][WT_LEN]
        int i = e & (WT_LEN - 1);
        float v = wtg[e];
        if (c >= 4) v = tanhf(v);
        wt_lds[i * N_WT + c] = v;
    }
    __syncthreads();                  // only barrier: wt table publication

    float4* slice4 = (float4*)(att_lds + w * (64 * N_WT));   // this wave's slice
    const float* my_att = att_lds + (w * 64 + lane) * N_WT;  // this lane's element

    for (int tile = blockIdx.x; tile < ntiles; tile += gridDim.x) {
        const int gbase = tile * 512;                 // tile is row-aligned (T_%512==0)
        const int row   = gbase >> 18;
        const float x0row = to_inc1(pitch[(size_t)row << 18]);

        const int ebase = gbase + w * 64;             // this wave's 64 elements
        const int gid   = ebase + lane;

        // stage att micro-tile: 320 float4, lane-coalesced (16 B lane stride)
        const float4* g4 = (const float4*)(att + (size_t)ebase * N_WT);
#pragma unroll
        for (int v = 0; v < 5; ++v)
            slice4[v * 64 + lane] = g4[v * 64 + lane];

        float S = Sbuf[gid];
        float y = S - x0row;              // index = cumsum - increment[:, :1]

        // exact fmod(y, 512)
        float qf  = floorf(y * (1.0f / 512.0f));
        float idx = fmaf(-512.0f, qf, y);
        if (idx < 0.0f)    idx += 512.0f;
        if (idx >= 512.0f) idx -= 512.0f;

        float fl0   = floorf(idx);
        float alpha = idx - fl0;
        int il = ((int)fl0) & (WT_LEN - 1);
        int ih = (il + (alpha > 0.0f ? 1 : 0)) & (WT_LEN - 1);

        const float4* lo4 = (const float4*)(&wt_lds[il * N_WT]);
        const float4* hi4 = (const float4*)(&wt_lds[ih * N_WT]);
        const float4* a4  = (const float4*)my_att;

        float acc = 0.0f;
#pragma unroll
        for (int v = 0; v < 5; ++v) {
            float4 lo = lo4[v];
            float4 hi = hi4[v];
            float4 at = a4[v];
            acc += at.x * (lo.x + alpha * (hi.x - lo.x));
            acc += at.y * (lo.y + alpha * (hi.y - lo.y));
            acc += at.z * (lo.z + alpha * (hi.z - lo.z));
            acc += at.w * (lo.w + alpha * (hi.w - lo.w));
        }
        out[gid] = acc * amp[gid];
    }
}

// ---------------------------------------------------------------------------
extern "C" void kernel_launch(void* const* d_in, const int* in_sizes, int n_in,
                              void* d_out, int out_size, void* d_ws, size_t ws_size,
                              hipStream_t stream) {
    const float* pitch = (const float*)d_in[0];
    const float* amp   = (const float*)d_in[1];
    const float* att   = (const float*)d_in[2];
    const float* wtg   = (const float*)d_in[3];

    float* A13 = (float*)d_ws;          // [512]
    float* S   = A13 + 1024;            // [TOTAL], 4 KB-aligned

    up_kernel<<<NCH, 1024, 0, stream>>>(pitch, A13);
    down_kernel<<<NCH, 1024, 0, stream>>>(pitch, A13, S);
    mix_kernel<<<1024, 512, 0, stream>>>(S, pitch, amp, att, wtg,
                                         (float*)d_out, TOTAL / 512);
}